// Round 1
// baseline (92.711 us; speedup 1.0000x reference)
//
#include <hip/hip_runtime.h>

#define N_QUBITS 4
#define N_LAYERS 6
#define NSTATES  16   // 2^N_QUBITS

__device__ __forceinline__ float2 cmul(float2 a, float2 b) {
    return make_float2(a.x * b.x - a.y * b.y, a.x * b.y + a.y * b.x);
}
__device__ __forceinline__ float2 cadd(float2 a, float2 b) {
    return make_float2(a.x + b.x, a.y + b.y);
}

// ---------------------------------------------------------------------------
// Fully fused kernel. Each block:
//   phase 1: rebuilds the batch-uniform 16x16 circuit unitary in its own LDS
//            (identical algorithm to the old build_u_kernel: 16 columns x 16
//            states, rolled gate loops, basis-permutation CNOTs). Redundant
//            across blocks but ~1-2 us of barrier-dominated work that
//            overlaps across the ~4 co-resident blocks/CU.
//   phase 2: per-thread RY product state v (real), amp = U @ v read straight
//            from LDS (wave-uniform broadcast reads, conflict-free), sign
//            butterfly, float4 store.
// This removes the separate 1-block build kernel, its launch latency, the
// inter-kernel serialization, and the U global round-trip (d_ws now unused).
// ---------------------------------------------------------------------------
__global__ __launch_bounds__(256) void qc_fused_kernel(
        const float* __restrict__ inputs,   // (B, 4)
        const float* __restrict__ weights,  // (6, 4, 3)
        float* __restrict__ out,            // (B, 4)
        int B) {
    __shared__ float2 rotm[N_LAYERS * N_QUBITS][4];
    __shared__ __align__(16) float2 st[NSTATES][NSTATES];   // [column k][state i]

    const int t = threadIdx.x;

    // --- phase 1: build U in LDS -------------------------------------------
    if (t < N_LAYERS * N_QUBITS) {
        const float phi   = weights[t * 3 + 0];
        const float theta = weights[t * 3 + 1];
        const float omega = weights[t * 3 + 2];
        float stheta, ctheta;
        sincosf(theta * 0.5f, &stheta, &ctheta);
        const float a1 = -(phi + omega) * 0.5f;
        const float a2 =  (phi - omega) * 0.5f;
        float s1, c1, s2, c2;
        sincosf(a1, &s1, &c1);
        sincosf(a2, &s2, &c2);
        rotm[t][0] = make_float2( c1 * ctheta,  s1 * ctheta);   // m00
        rotm[t][1] = make_float2(-c2 * stheta, -s2 * stheta);   // m01
        rotm[t][2] = make_float2( c2 * stheta, -s2 * stheta);   // m10
        rotm[t][3] = make_float2( c1 * ctheta, -s1 * ctheta);   // m11
    }

    const int c = t >> 4;     // column (input basis state)
    const int i = t & 15;     // state index within the column's vector
    st[c][i] = make_float2(i == c ? 1.0f : 0.0f, 0.0f);
    __syncthreads();

    #pragma unroll 1
    for (int l = 0; l < N_LAYERS; ++l) {
        // Rot gates on each wire
        #pragma unroll 1
        for (int w = 0; w < N_QUBITS; ++w) {
            const int bit = 8 >> w;
            if (!(i & bit)) {
                const int j = i | bit;
                const float2 a0  = st[c][i];
                const float2 a1v = st[c][j];
                const float2 m00 = rotm[l * N_QUBITS + w][0];
                const float2 m01 = rotm[l * N_QUBITS + w][1];
                const float2 m10 = rotm[l * N_QUBITS + w][2];
                const float2 m11 = rotm[l * N_QUBITS + w][3];
                st[c][i] = cadd(cmul(m00, a0), cmul(m01, a1v));
                st[c][j] = cadd(cmul(m10, a0), cmul(m11, a1v));
            }
            __syncthreads();
        }
        // ring of CNOTs, range r: basis-label permutation
        const int r = l % (N_QUBITS - 1) + 1;
        int fi = i;
        #pragma unroll
        for (int w = 0; w < N_QUBITS; ++w) {
            const int tb = 8 >> ((w + r) & 3);
            if ((fi >> (3 - w)) & 1) fi ^= tb;   // CNOT: target ^= control
        }
        const float2 a = st[c][i];
        __syncthreads();
        st[c][fi] = a;
        __syncthreads();   // U fully built & visible after last iteration
    }

    // --- phase 2: per-sample apply -----------------------------------------
    const int b = blockIdx.x * blockDim.x + t;
    if (b >= B) return;   // after all barriers (B is a multiple of 256 anyway)

    const float4 xin = reinterpret_cast<const float4*>(inputs)[b];
    float s0, c0, s1, c1, s2, c2, s3, c3;
    __sincosf(xin.x * 0.5f, &s0, &c0);
    __sincosf(xin.y * 0.5f, &s1, &c1);
    __sincosf(xin.z * 0.5f, &s2, &c2);
    __sincosf(xin.w * 0.5f, &s3, &c3);

    // v[i], i bits (b3 b2 b1 b0) = wires (0,1,2,3); bit=1 -> sin
    const float vA[4] = { c0 * c1, c0 * s1, s0 * c1, s0 * s1 };  // wires 0,1
    const float vB[4] = { c2 * c3, c2 * s3, s2 * c3, s2 * s3 };  // wires 2,3
    float v[NSTATES];
    #pragma unroll
    for (int a = 0; a < 4; ++a)
        #pragma unroll
        for (int q = 0; q < 4; ++q)
            v[a * 4 + q] = vA[a] * vB[q];

    // amp = U @ v, with U[i][k] = st[k][i]: accumulate columns scaled by v[k].
    // st[k][0..15] is 128 B contiguous -> 4x float4 per column, wave-uniform
    // address -> LDS broadcast, no bank conflicts. Fully unrolled so v/amp
    // stay in registers.
    float2 amp[NSTATES];
    #pragma unroll
    for (int q = 0; q < NSTATES; ++q) amp[q] = make_float2(0.0f, 0.0f);

    #pragma unroll
    for (int k = 0; k < NSTATES; ++k) {
        const float vk = v[k];
        const float4* col = reinterpret_cast<const float4*>(&st[k][0]);
        #pragma unroll
        for (int j = 0; j < 8; ++j) {          // 8 float4 = 16 complex entries
            const float4 u4 = col[j];
            amp[2 * j].x     = fmaf(vk, u4.x, amp[2 * j].x);
            amp[2 * j].y     = fmaf(vk, u4.y, amp[2 * j].y);
            amp[2 * j + 1].x = fmaf(vk, u4.z, amp[2 * j + 1].x);
            amp[2 * j + 1].y = fmaf(vk, u4.w, amp[2 * j + 1].y);
        }
    }

    float p[NSTATES];
    #pragma unroll
    for (int q = 0; q < NSTATES; ++q)
        p[q] = amp[q].x * amp[q].x + amp[q].y * amp[q].y;

    // Sign butterfly: z_w = sum_i (1 - 2*bit_{3-w}(i)) * p[i]
    float sa[8], da[8];
    #pragma unroll
    for (int j = 0; j < 8; ++j) {
        sa[j] = p[2 * j] + p[2 * j + 1];
        da[j] = p[2 * j] - p[2 * j + 1];
    }
    const float z3 = ((da[0] + da[1]) + (da[2] + da[3])) +
                     ((da[4] + da[5]) + (da[6] + da[7]));
    float sb[4], db[4];
    #pragma unroll
    for (int j = 0; j < 4; ++j) {
        sb[j] = sa[2 * j] + sa[2 * j + 1];
        db[j] = sa[2 * j] - sa[2 * j + 1];
    }
    const float z2 = (db[0] + db[1]) + (db[2] + db[3]);
    const float z1 = (sb[0] - sb[1]) + (sb[2] - sb[3]);
    const float z0 = (sb[0] + sb[1]) - (sb[2] + sb[3]);

    reinterpret_cast<float4*>(out)[b] = make_float4(z0, z1, z2, z3);
}

extern "C" void kernel_launch(void* const* d_in, const int* in_sizes, int n_in,
                              void* d_out, int out_size, void* d_ws, size_t ws_size,
                              hipStream_t stream) {
    const float* inputs  = (const float*)d_in[0];   // (B, 4) float32
    const float* weights = (const float*)d_in[1];   // (6, 4, 3) float32
    float* out = (float*)d_out;                     // (B, 4) float32
    const int B = in_sizes[0] / N_QUBITS;

    const int block = 256;
    const int grid = (B + block - 1) / block;
    qc_fused_kernel<<<grid, block, 0, stream>>>(inputs, weights, out, B);
}

// Round 2
// 70.104 us; speedup vs baseline: 1.3225x; 1.3225x over previous
//
#include <hip/hip_runtime.h>

#define N_QUBITS 4
#define N_LAYERS 6
#define NSTATES  16   // 2^N_QUBITS

__device__ __forceinline__ float2 cmul(float2 a, float2 b) {
    return make_float2(a.x * b.x - a.y * b.y, a.x * b.y + a.y * b.x);
}
__device__ __forceinline__ float2 cadd(float2 a, float2 b) {
    return make_float2(a.x + b.x, a.y + b.y);
}

// ---------------------------------------------------------------------------
// Build kernel: ONE wave (64 threads), zero barrier ladder.
//   lanes 0..23 : compute the 24 Rot gate matrices -> LDS (one 1-wave sync)
//   lanes 0..15 : each evolves ONE column of U entirely in registers
//                 (16 x float2). Layer/wire loops fully unrolled, so the
//                 CNOT ring is a compile-time register permutation (free).
// Replaces the old 256-thread LDS version with its 26 x 4-wave barriers.
// U row-major interleaved re/im: U[2*(i*16+c)+{0,1}] = <i|U|c>.
// ---------------------------------------------------------------------------
__global__ __launch_bounds__(64) void build_u_kernel(
        const float* __restrict__ weights, float* __restrict__ U) {
    __shared__ float2 rotm[N_LAYERS * N_QUBITS][4];

    const int t = threadIdx.x;
    if (t < N_LAYERS * N_QUBITS) {
        const float phi   = weights[t * 3 + 0];
        const float theta = weights[t * 3 + 1];
        const float omega = weights[t * 3 + 2];
        float stheta, ctheta;
        sincosf(theta * 0.5f, &stheta, &ctheta);
        const float a1 = -(phi + omega) * 0.5f;
        const float a2 =  (phi - omega) * 0.5f;
        float s1, c1, s2, c2;
        sincosf(a1, &s1, &c1);
        sincosf(a2, &s2, &c2);
        rotm[t][0] = make_float2( c1 * ctheta,  s1 * ctheta);   // m00
        rotm[t][1] = make_float2(-c2 * stheta, -s2 * stheta);   // m01
        rotm[t][2] = make_float2( c2 * stheta, -s2 * stheta);   // m10
        rotm[t][3] = make_float2( c1 * ctheta, -s1 * ctheta);   // m11
    }
    __syncthreads();   // single-wave block: essentially just a waitcnt

    if (t < NSTATES) {
        const int c = t;                 // this lane's column
        float2 s[NSTATES];
        #pragma unroll
        for (int q = 0; q < NSTATES; ++q)
            s[q] = make_float2(q == c ? 1.0f : 0.0f, 0.0f);

        #pragma unroll
        for (int l = 0; l < N_LAYERS; ++l) {
            // Rot gates on each wire (LDS reads are wave-uniform -> broadcast)
            #pragma unroll
            for (int w = 0; w < N_QUBITS; ++w) {
                const float2 m00 = rotm[l * N_QUBITS + w][0];
                const float2 m01 = rotm[l * N_QUBITS + w][1];
                const float2 m10 = rotm[l * N_QUBITS + w][2];
                const float2 m11 = rotm[l * N_QUBITS + w][3];
                const int bit = 8 >> w;
                #pragma unroll
                for (int i = 0; i < NSTATES; ++i) {
                    if (i & bit) continue;
                    const int j = i | bit;
                    const float2 a0 = s[i];
                    const float2 a1v = s[j];
                    s[i] = cadd(cmul(m00, a0), cmul(m01, a1v));
                    s[j] = cadd(cmul(m10, a0), cmul(m11, a1v));
                }
            }
            // ring of CNOTs, range r: compile-time basis-label permutation
            const int r = l % (N_QUBITS - 1) + 1;
            float2 tmp[NSTATES];
            #pragma unroll
            for (int i = 0; i < NSTATES; ++i) {
                int fi = i;
                #pragma unroll
                for (int w = 0; w < N_QUBITS; ++w) {
                    const int tb = 8 >> ((w + r) & 3);
                    if ((fi >> (3 - w)) & 1) fi ^= tb;   // CNOT: target ^= control
                }
                tmp[fi] = s[i];
            }
            #pragma unroll
            for (int i = 0; i < NSTATES; ++i) s[i] = tmp[i];
        }

        // store column c: U[i][c]
        #pragma unroll
        for (int i = 0; i < NSTATES; ++i)
            reinterpret_cast<float2*>(U)[i * NSTATES + c] = s[i];
    }
}

// ---------------------------------------------------------------------------
// Apply kernel: v = RY product state (real), amp = U @ v, signs folded into
// the row loop (compile-time +/-, no p[16] array, no butterfly).
// GUARD=false variant has NO divergent control flow -> the wave-uniform U
// row loads (compile-time offsets) are eligible for scalarization (s_load),
// keeping them off the vector-memory/LDS critical path.
// ---------------------------------------------------------------------------
template<bool GUARD>
__global__ __launch_bounds__(256) void qc_apply_kernel(
        const float* __restrict__ inputs,   // (B, 4)
        const float* __restrict__ U,        // 16x16 complex, interleaved
        float* __restrict__ out,            // (B, 4)
        int B) {
    const int b = blockIdx.x * 256 + threadIdx.x;
    if (GUARD && b >= B) return;

    const float4 xin = reinterpret_cast<const float4*>(inputs)[b];
    float s0, c0, s1, c1, s2, c2, s3, c3;
    __sincosf(xin.x * 0.5f, &s0, &c0);
    __sincosf(xin.y * 0.5f, &s1, &c1);
    __sincosf(xin.z * 0.5f, &s2, &c2);
    __sincosf(xin.w * 0.5f, &s3, &c3);

    // v[i], i bits (b3 b2 b1 b0) = wires (0,1,2,3); bit=1 -> sin
    const float vA[4] = { c0 * c1, c0 * s1, s0 * c1, s0 * s1 };  // wires 0,1
    const float vB[4] = { c2 * c3, c2 * s3, s2 * c3, s2 * s3 };  // wires 2,3
    float v[NSTATES];
    #pragma unroll
    for (int a = 0; a < 4; ++a)
        #pragma unroll
        for (int q = 0; q < 4; ++q)
            v[a * 4 + q] = vA[a] * vB[q];

    float z0 = 0.0f, z1 = 0.0f, z2 = 0.0f, z3 = 0.0f;
    #pragma unroll
    for (int i = 0; i < NSTATES; ++i) {
        const float4* row = reinterpret_cast<const float4*>(U + 2 * NSTATES * i);
        float re = 0.0f, im = 0.0f;
        #pragma unroll
        for (int q = 0; q < 8; ++q) {          // 8 float4 = 16 complex entries
            const float4 u4 = row[q];
            re = fmaf(u4.x, v[2 * q],     re);
            im = fmaf(u4.y, v[2 * q],     im);
            re = fmaf(u4.z, v[2 * q + 1], re);
            im = fmaf(u4.w, v[2 * q + 1], im);
        }
        const float p = re * re + im * im;
        // z_w = sum_i (1 - 2*bit_{3-w}(i)) * p[i]; i is compile-time here
        z0 = (i & 8) ? z0 - p : z0 + p;
        z1 = (i & 4) ? z1 - p : z1 + p;
        z2 = (i & 2) ? z2 - p : z2 + p;
        z3 = (i & 1) ? z3 - p : z3 + p;
    }

    reinterpret_cast<float4*>(out)[b] = make_float4(z0, z1, z2, z3);
}

extern "C" void kernel_launch(void* const* d_in, const int* in_sizes, int n_in,
                              void* d_out, int out_size, void* d_ws, size_t ws_size,
                              hipStream_t stream) {
    const float* inputs  = (const float*)d_in[0];   // (B, 4) float32
    const float* weights = (const float*)d_in[1];   // (6, 4, 3) float32
    float* out = (float*)d_out;                     // (B, 4) float32
    float* U   = (float*)d_ws;                      // 512 floats scratch
    const int B = in_sizes[0] / N_QUBITS;

    build_u_kernel<<<1, 64, 0, stream>>>(weights, U);

    if ((B & 255) == 0) {
        qc_apply_kernel<false><<<B / 256, 256, 0, stream>>>(inputs, U, out, B);
    } else {
        qc_apply_kernel<true><<<(B + 255) / 256, 256, 0, stream>>>(inputs, U, out, B);
    }
}